// Round 6
// baseline (119.714 us; speedup 1.0000x reference)
//
#include <hip/hip_runtime.h>

// NodeEdgeProjection: out[b, e, f] = x[b, e/127, f]
// B=128, N=128, n_edges = 128*127 = 16256, F=64, fp32.
//
// Round-5: mimic the harness fill kernel's stream structure (2.13 GB @ 6.9
// TB/s at 11% occupancy ~= 1024 waves, each marching a long contiguous span).
// Ladder: tiny+nt 103.1 | fat+plain 106.6 | fat+nt 113.6 | stride+plain 117.2
// -> all ~5.1 TB/s with 8192 waves x interleaved-4KB streams. Few long
// sequential streams is the DRAM row-buffer-friendly pattern; copy it.
//
// Grid = 256 blocks (1/CU) x 4 waves = 1024 waves. Wave w owns node-pairs
// [16w, 16w+16): prefetch all 16 x rows into regs (64 VGPR), then write its
// 520 KB output span front-to-back, 4 KB (4 rows x 64 floats) per
// wave-store-instruction. Plain cached stores (fill's config, no nt).

typedef float f32x4 __attribute__((ext_vector_type(4)));

constexpr unsigned Nn  = 128;
constexpr unsigned REP = Nn - 1;          // 127 replicas per node
constexpr unsigned F4  = 16;              // float4 per 64-float row
constexpr unsigned NPW = 16;              // node-pairs per wave
constexpr unsigned WAVES = 1024;          // 128*128/16

__global__ __launch_bounds__(256) void node_edge_streams(
    const f32x4* __restrict__ x, f32x4* __restrict__ out) {
    const unsigned tid  = threadIdx.x;
    const unsigned lane = tid & 63;
    const unsigned wid  = blockIdx.x * 4 + (tid >> 6);   // global wave 0..1023
    const unsigned f4   = lane & (F4 - 1);               // feature quad 0..15
    const unsigned rg0  = lane >> 4;                     // row-group lane 0..3

    const unsigned pair0 = wid * NPW;                    // b*128+node, 16 consecutive

    // Prefetch all 16 node rows for this wave into registers (no loads later).
    f32x4 v[NPW];
    #pragma unroll
    for (unsigned n = 0; n < NPW; ++n)
        v[n] = x[(pair0 + n) * F4 + f4];

    // Stream the wave's contiguous 520 KB span front-to-back.
    // Per node: 127 rows; wave-iteration covers rows r..r+3 (4 KB contiguous).
    f32x4* dst = out + (size_t)pair0 * REP * F4 + f4;
    #pragma unroll
    for (unsigned n = 0; n < NPW; ++n) {
        f32x4* dn = dst + n * REP * F4;
        #pragma unroll 8
        for (unsigned r = rg0; r < REP; r += 4) {
            dn[r * F4] = v[n];
        }
    }
}

extern "C" void kernel_launch(void* const* d_in, const int* in_sizes, int n_in,
                              void* d_out, int out_size, void* d_ws, size_t ws_size,
                              hipStream_t stream) {
    const f32x4* x = (const f32x4*)d_in[0];
    f32x4* out = (f32x4*)d_out;

    node_edge_streams<<<WAVES / 4, 256, 0, stream>>>(x, out);
}